// Round 9
// baseline (94.588 us; speedup 1.0000x reference)
//
#include <hip/hip_runtime.h>
#include <hip/hip_bf16.h>

#define HALF 4096
#define NTOT 8192
#define D 128
#define KS2 3.79828256f   // sqrt(10*log2(e)); acc = s_ij*log2(e), e = exp2(acc)

typedef __attribute__((ext_vector_type(8))) short bf16x8;
typedef __attribute__((ext_vector_type(4))) float f32x4;

__device__ __forceinline__ float wave_sum64(float v) {
#pragma unroll
    for (int m = 32; m >= 1; m >>= 1) v += __shfl_xor(v, m);
    return v;
}

__device__ __forceinline__ unsigned short tobf(float v) {
    __hip_bfloat16 b = __float2bfloat16(v);
    return *(unsigned short*)&b;
}

// One wave per pair b. Writes x*KS2 as bf16 in MFMA-fragment-packed layout:
// element offset ((g*4+k)*64 + quad*16 + lrow)*8 + j <-> X[g*16+lrow][k*32+quad*8+j].
// Also: spos[b] (exact fp32 positive dot), sii2[row] = log2-scaled self-sim
// from the SAME bf16-rounded values (diagonal subtraction in finalize), and
// zero-init of the gram work-queue / accumulator / done counters.
__global__ void cast_pos_kernel(const float* __restrict__ f1, const float* __restrict__ f2,
                                unsigned short* __restrict__ xs, float* __restrict__ spos,
                                float* __restrict__ sii2, unsigned int* __restrict__ qctr,
                                float* __restrict__ acc, unsigned int* __restrict__ done) {
    if (blockIdx.x == 0 && threadIdx.x == 0) { *qctr = 0u; *acc = 0.f; *done = 0u; }
    int w = (blockIdx.x * blockDim.x + threadIdx.x) >> 6;   // pair index b, 0..4095
    int l = threadIdx.x & 63;
    float2 a1 = ((const float2*)(f1 + (size_t)w * D))[l];
    float2 a2 = ((const float2*)(f2 + (size_t)w * D))[l];

    ushort2 v1, v2;
    v1.x = tobf(a1.x * KS2); v1.y = tobf(a1.y * KS2);
    v2.x = tobf(a2.x * KS2); v2.y = tobf(a2.y * KS2);

    // this thread covers X[w][2l..2l+2): k = l>>4, quad = (l>>2)&3, j = (l&3)*2
    int g = w >> 4, lrow = w & 15;
    int k = l >> 4, quad = (l >> 2) & 3, j = (l & 3) * 2;
    size_t off = ((size_t)(g * 4 + k) * 64 + quad * 16 + lrow) * 8 + j;
    *(ushort2*)(xs + off)              = v1;                 // row w
    *(ushort2*)(xs + off + 256 * 2048) = v2;                 // row w+HALF

    float b1x = __uint_as_float((unsigned)v1.x << 16), b1y = __uint_as_float((unsigned)v1.y << 16);
    float b2x = __uint_as_float((unsigned)v2.x << 16), b2y = __uint_as_float((unsigned)v2.y << 16);
    float s1 = b1x * b1x + b1y * b1y;
    float s2 = b2x * b2x + b2y * b2y;
    float d  = a1.x * a2.x + a1.y * a2.y;
    s1 = wave_sum64(s1); s2 = wave_sum64(s2); d = wave_sum64(d);
    if (l == 0) {
        sii2[w] = s1; sii2[w + HALF] = s2;
        float sp = d * 10.0f;
        spos[w] = sp; spos[w + HALF] = sp;
    }
}

// LDS-free Gram row-sum sweep on packed operands (L2-resident), persistent
// blocks + atomic work queue over 1024 (slab,panel) units (no co-residency
// assumption: blocks never wait on each other, any dispatch order is correct).
// 768 blocks = exactly 3/CU -> no static-partition tail. Per unit: wave covers
// 64 rows x 32 cols per step; acc[4][2]=32 AGPRs, af[4][4]=64 VGPRs hoisted
// once. R7 rotated pipeline: MFMA consumes bfr, next tile's loads re-issue
// into the SAME regs (WAR-safe), exp2 block overlaps the L2 latency.
// tt loop stays rolled (full unroll => spill, R5 post-mortem).
__global__ __launch_bounds__(256, 3) void gram_kernel(const unsigned short* __restrict__ xs,
                                                      float* __restrict__ E1p,
                                                      unsigned int* __restrict__ qctr) {
    const int t = threadIdx.x;
    const int wave = t >> 6, lane = t & 63;
    const int lrow = lane & 15, quad = lane >> 4;
    __shared__ unsigned int su;

#pragma unroll 1
    for (;;) {
        __syncthreads();
        if (t == 0) su = atomicAdd(qctr, 1u);
        __syncthreads();
        unsigned int u = su;
        if (u >= 1024u) break;
        const int slab = (int)(u >> 7);       // 0..7   (slab-major: consecutive
        const int panel = (int)(u & 127u);    // 0..127  units share the B slab)

        // A fragments: row groups g = panel*4 + r; offset (g*4+k)*512 + lane*8
        const unsigned short* ab = xs + (size_t)panel * 16 * 512 + lane * 8;
        bf16x8 af[4][4];
#pragma unroll
        for (int k = 0; k < 4; ++k)
#pragma unroll
            for (int r = 0; r < 4; ++r)
                af[k][r] = *(const bf16x8*)(ab + (r * 4 + k) * 512);

        // B base: col group = slab*64 + tt*8 + wave*2 + c
        const unsigned short* bb = xs + ((size_t)slab * 64 + wave * 2) * 2048 + lane * 8;
        bf16x8 bfr[4][2];
#pragma unroll
        for (int k = 0; k < 4; ++k)
#pragma unroll
            for (int c = 0; c < 2; ++c)
                bfr[k][c] = *(const bf16x8*)(bb + (c * 4 + k) * 512);

        f32x4 rs4[4];
#pragma unroll
        for (int r = 0; r < 4; ++r) rs4[r] = (f32x4){0.f, 0.f, 0.f, 0.f};

#pragma unroll 1
        for (int tt = 0; tt < 8; ++tt) {
            f32x4 a2[4][2];
#pragma unroll
            for (int r = 0; r < 4; ++r)
#pragma unroll
                for (int c = 0; c < 2; ++c) a2[r][c] = (f32x4){0.f, 0.f, 0.f, 0.f};
#pragma unroll
            for (int k = 0; k < 4; ++k)
#pragma unroll
                for (int r = 0; r < 4; ++r)
#pragma unroll
                    for (int c = 0; c < 2; ++c)
                        a2[r][c] = __builtin_amdgcn_mfma_f32_16x16x32_bf16(af[k][r], bfr[k][c], a2[r][c], 0, 0, 0);
            if (tt < 7) {   // rotate: next tile's loads into the same regs
                const unsigned short* bn = bb + (size_t)(tt + 1) * 8 * 2048;
#pragma unroll
                for (int k = 0; k < 4; ++k)
#pragma unroll
                    for (int c = 0; c < 2; ++c)
                        bfr[k][c] = *(const bf16x8*)(bn + (c * 4 + k) * 512);
            }
#pragma unroll
            for (int r = 0; r < 4; ++r)
#pragma unroll
                for (int c = 0; c < 2; ++c)
#pragma unroll
                    for (int g = 0; g < 4; ++g)
                        rs4[r][g] += __builtin_amdgcn_exp2f(a2[r][c][g]);
        }

        const int slot = slab * 4 + wave;   // disjoint (slot,row) per unit
#pragma unroll
        for (int r = 0; r < 4; ++r) {
#pragma unroll
            for (int g = 0; g < 4; ++g) {
                float v = rs4[r][g];
#pragma unroll
                for (int m = 1; m <= 8; m <<= 1) v += __shfl_xor(v, m);
                if (lrow == 0)
                    E1p[(size_t)slot * NTOT + panel * 64 + r * 16 + quad * 4 + g] = v;
            }
        }
    }
}

// 32 blocks x 256: per-row closed form. div = sum(slots) - exp2(sii2) [diag].
// sum_j log1p(-P_ij) ~= -1  (sum_j P_ij == 1 exactly; S2/2 ~ 1e-4 dropped).
// Device-scope done-counter: last-finishing block writes the output (safe
// without co-residency — nobody waits, atomics are device-scope).
__global__ void rowterm_kernel(const float* __restrict__ E1p, const float* __restrict__ spos,
                               const float* __restrict__ sii2, float* __restrict__ acc,
                               unsigned int* __restrict__ done, float* __restrict__ out) {
    int i = blockIdx.x * 256 + threadIdx.x;
    float div = 0.f;
#pragma unroll
    for (int s = 0; s < 32; ++s) div += E1p[(size_t)s * NTOT + i];
    div -= __builtin_amdgcn_exp2f(sii2[i]);
    float sp = spos[i];
    float pmt = __expf(sp) / div;
    float term = sp - __logf(div) - 1.0f - __logf(1.0f - pmt);

    term = wave_sum64(term);
    __shared__ float red[4];
    if ((threadIdx.x & 63) == 0) red[threadIdx.x >> 6] = term;
    __syncthreads();
    if (threadIdx.x == 0) {
        atomicAdd(acc, red[0] + red[1] + red[2] + red[3]);
        __threadfence();
        unsigned int prev = atomicAdd(done, 1u);
        if (prev == 31u) {   // last block: atomic read-back, single write
            float total = atomicAdd(acc, 0.0f);
            out[0] = -total * (1.0f / (float)NTOT);
        }
    }
}

extern "C" void kernel_launch(void* const* d_in, const int* in_sizes, int n_in,
                              void* d_out, int out_size, void* d_ws, size_t ws_size,
                              hipStream_t stream) {
    const float* f1 = (const float*)d_in[0];
    const float* f2 = (const float*)d_in[1];
    float* out = (float*)d_out;

    char* ws = (char*)d_ws;
    unsigned short* xs = (unsigned short*)ws;                 // 2 MB packed bf16
    float* E1p  = (float*)(ws + (size_t)NTOT * D * 2);        // 32*8192 f32 = 1 MB
    float* spos = E1p + 32 * NTOT;                            // 8192 f32
    float* sii2 = spos + NTOT;                                // 8192 f32
    float* acc  = sii2 + NTOT;                                // 1 f32
    unsigned int* done = (unsigned int*)(acc + 1);
    unsigned int* qctr = done + 1;

    cast_pos_kernel<<<1024, 256, 0, stream>>>(f1, f2, xs, spos, sii2, qctr, acc, done);
    gram_kernel<<<768, 256, 0, stream>>>(xs, E1p, qctr);
    rowterm_kernel<<<32, 256, 0, stream>>>(E1p, spos, sii2, acc, done, out);
}

// Round 10
// 82.555 us; speedup vs baseline: 1.1457x; 1.1457x over previous
//
#include <hip/hip_runtime.h>
#include <hip/hip_bf16.h>

#define HALF 4096
#define NTOT 8192
#define D 128
#define KS2 3.79828256f   // sqrt(10*log2(e)); acc = s_ij*log2(e), e = exp2(acc)

typedef __attribute__((ext_vector_type(8))) short bf16x8;
typedef __attribute__((ext_vector_type(4))) float f32x4;

__device__ __forceinline__ float wave_sum64(float v) {
#pragma unroll
    for (int m = 32; m >= 1; m >>= 1) v += __shfl_xor(v, m);
    return v;
}

__device__ __forceinline__ unsigned short tobf(float v) {
    __hip_bfloat16 b = __float2bfloat16(v);
    return *(unsigned short*)&b;
}

// One wave per pair b. Writes x*KS2 as bf16 in MFMA-fragment-packed layout:
// element offset ((g*4+k)*64 + quad*16 + lrow)*8 + j <-> X[g*16+lrow][k*32+quad*8+j].
// Also: spos[b] (exact fp32 positive dot), sii2[row] = log2-scaled self-sim
// from the SAME bf16-rounded values (diagonal subtraction in finalize), and
// zero-init of the accumulator / done counters used by rowterm.
__global__ void cast_pos_kernel(const float* __restrict__ f1, const float* __restrict__ f2,
                                unsigned short* __restrict__ xs, float* __restrict__ spos,
                                float* __restrict__ sii2, float* __restrict__ acc,
                                unsigned int* __restrict__ done) {
    if (blockIdx.x == 0 && threadIdx.x == 0) { *acc = 0.f; *done = 0u; }
    int w = (blockIdx.x * blockDim.x + threadIdx.x) >> 6;   // pair index b, 0..4095
    int l = threadIdx.x & 63;
    float2 a1 = ((const float2*)(f1 + (size_t)w * D))[l];
    float2 a2 = ((const float2*)(f2 + (size_t)w * D))[l];

    ushort2 v1, v2;
    v1.x = tobf(a1.x * KS2); v1.y = tobf(a1.y * KS2);
    v2.x = tobf(a2.x * KS2); v2.y = tobf(a2.y * KS2);

    // this thread covers X[w][2l..2l+2): k = l>>4, quad = (l>>2)&3, j = (l&3)*2
    int g = w >> 4, lrow = w & 15;
    int k = l >> 4, quad = (l >> 2) & 3, j = (l & 3) * 2;
    size_t off = ((size_t)(g * 4 + k) * 64 + quad * 16 + lrow) * 8 + j;
    *(ushort2*)(xs + off)              = v1;                 // row w
    *(ushort2*)(xs + off + 256 * 2048) = v2;                 // row w+HALF

    float b1x = __uint_as_float((unsigned)v1.x << 16), b1y = __uint_as_float((unsigned)v1.y << 16);
    float b2x = __uint_as_float((unsigned)v2.x << 16), b2y = __uint_as_float((unsigned)v2.y << 16);
    float s1 = b1x * b1x + b1y * b1y;
    float s2 = b2x * b2x + b2y * b2y;
    float d  = a1.x * a2.x + a1.y * a2.y;
    s1 = wave_sum64(s1); s2 = wave_sum64(s2); d = wave_sum64(d);
    if (l == 0) {
        sii2[w] = s1; sii2[w + HALF] = s2;
        float sp = d * 10.0f;
        spos[w] = sp; spos[w + HALF] = sp;
    }
}

// LDS-free, barrier-free Gram row-sum sweep on packed operands (L2-resident).
// STATIC single-round grid: 512 blocks = exactly 2/CU, perfectly balanced
// (R9 post-mortem: dynamic queue serializes waves between units — regressed;
// R7's 1024 blocks had a 256-block straggler round). Block (slab 0..3,
// panel 0..127): rows panel*64..+63, cols slab*2048..+2047 over 16 tile-steps.
// Wave: 64 rows x 32 cols per step; acc[4][2]=32 AGPRs, af[4][4]=64 VGPRs
// hoisted once. Rotated pipeline: MFMA consumes bfr, next tile's loads
// re-issue into the SAME regs (WAR-safe), exp2 block overlaps the L2 latency.
// tt loop stays rolled (full unroll => spill, R5 post-mortem).
__global__ __launch_bounds__(256, 2) void gram_kernel(const unsigned short* __restrict__ xs,
                                                      float* __restrict__ E1p) {
    const int slab = blockIdx.x;    // 0..3
    const int panel = blockIdx.y;   // 0..127
    const int t = threadIdx.x;
    const int wave = t >> 6, lane = t & 63;
    const int lrow = lane & 15, quad = lane >> 4;

    // A fragments: row groups g = panel*4 + r; offset (g*4+k)*512 + lane*8
    const unsigned short* ab = xs + (size_t)panel * 16 * 512 + lane * 8;
    bf16x8 af[4][4];
#pragma unroll
    for (int k = 0; k < 4; ++k)
#pragma unroll
        for (int r = 0; r < 4; ++r)
            af[k][r] = *(const bf16x8*)(ab + (r * 4 + k) * 512);

    // B base: col group = slab*128 + tt*8 + wave*2 + c (group stride 2048 elems)
    const unsigned short* bb = xs + ((size_t)slab * 128 + wave * 2) * 2048 + lane * 8;
    bf16x8 bfr[4][2];
#pragma unroll
    for (int k = 0; k < 4; ++k)
#pragma unroll
        for (int c = 0; c < 2; ++c)
            bfr[k][c] = *(const bf16x8*)(bb + (c * 4 + k) * 512);

    f32x4 rs4[4];
#pragma unroll
    for (int r = 0; r < 4; ++r) rs4[r] = (f32x4){0.f, 0.f, 0.f, 0.f};

#pragma unroll 1
    for (int tt = 0; tt < 16; ++tt) {
        f32x4 a2[4][2];
#pragma unroll
        for (int r = 0; r < 4; ++r)
#pragma unroll
            for (int c = 0; c < 2; ++c) a2[r][c] = (f32x4){0.f, 0.f, 0.f, 0.f};
#pragma unroll
        for (int k = 0; k < 4; ++k)
#pragma unroll
            for (int r = 0; r < 4; ++r)
#pragma unroll
                for (int c = 0; c < 2; ++c)
                    a2[r][c] = __builtin_amdgcn_mfma_f32_16x16x32_bf16(af[k][r], bfr[k][c], a2[r][c], 0, 0, 0);

        if (tt < 15) {   // rotate: next tile's loads into the same regs
            const unsigned short* bn = bb + (size_t)(tt + 1) * 8 * 2048;
#pragma unroll
            for (int k = 0; k < 4; ++k)
#pragma unroll
                for (int c = 0; c < 2; ++c)
                    bfr[k][c] = *(const bf16x8*)(bn + (c * 4 + k) * 512);
        }

#pragma unroll
        for (int r = 0; r < 4; ++r)
#pragma unroll
            for (int c = 0; c < 2; ++c)
#pragma unroll
                for (int g = 0; g < 4; ++g)
                    rs4[r][g] += __builtin_amdgcn_exp2f(a2[r][c][g]);
    }

    // reduce over the 16 lanes sharing a quad; disjoint-slot store (no atomics)
    const int slot = slab * 4 + wave;   // 0..15
#pragma unroll
    for (int r = 0; r < 4; ++r) {
#pragma unroll
        for (int g = 0; g < 4; ++g) {
            float v = rs4[r][g];
#pragma unroll
            for (int m = 1; m <= 8; m <<= 1) v += __shfl_xor(v, m);
            if (lrow == 0)
                E1p[(size_t)slot * NTOT + panel * 64 + r * 16 + quad * 4 + g] = v;
        }
    }
}

// 32 blocks x 256: per-row closed form. div = sum(16 slots) - exp2(sii2).
// sum_j log1p(-P_ij) ~= -1  (sum_j P_ij == 1 exactly; S2/2 ~ 1e-4 dropped).
// Device-scope done-counter: last-finishing block writes the output (proven
// in R9; safe without co-residency — nobody waits, atomics device-scope).
__global__ void rowterm_kernel(const float* __restrict__ E1p, const float* __restrict__ spos,
                               const float* __restrict__ sii2, float* __restrict__ acc,
                               unsigned int* __restrict__ done, float* __restrict__ out) {
    int i = blockIdx.x * 256 + threadIdx.x;
    float div = 0.f;
#pragma unroll
    for (int s = 0; s < 16; ++s) div += E1p[(size_t)s * NTOT + i];
    div -= __builtin_amdgcn_exp2f(sii2[i]);
    float sp = spos[i];
    float pmt = __expf(sp) / div;
    float term = sp - __logf(div) - 1.0f - __logf(1.0f - pmt);

    term = wave_sum64(term);
    __shared__ float red[4];
    if ((threadIdx.x & 63) == 0) red[threadIdx.x >> 6] = term;
    __syncthreads();
    if (threadIdx.x == 0) {
        atomicAdd(acc, red[0] + red[1] + red[2] + red[3]);
        __threadfence();
        unsigned int prev = atomicAdd(done, 1u);
        if (prev == 31u) {   // last block: atomic read-back, single write
            float total = atomicAdd(acc, 0.0f);
            out[0] = -total * (1.0f / (float)NTOT);
        }
    }
}

extern "C" void kernel_launch(void* const* d_in, const int* in_sizes, int n_in,
                              void* d_out, int out_size, void* d_ws, size_t ws_size,
                              hipStream_t stream) {
    const float* f1 = (const float*)d_in[0];
    const float* f2 = (const float*)d_in[1];
    float* out = (float*)d_out;

    char* ws = (char*)d_ws;
    unsigned short* xs = (unsigned short*)ws;                 // 2 MB packed bf16
    float* E1p  = (float*)(ws + (size_t)NTOT * D * 2);        // 16*8192 f32 = 512 KB
    float* spos = E1p + 16 * NTOT;                            // 8192 f32
    float* sii2 = spos + NTOT;                                // 8192 f32
    float* acc  = sii2 + NTOT;                                // 1 f32
    unsigned int* done = (unsigned int*)(acc + 1);

    cast_pos_kernel<<<1024, 256, 0, stream>>>(f1, f2, xs, spos, sii2, acc, done);
    gram_kernel<<<dim3(4, 128), 256, 0, stream>>>(xs, E1p);
    rowterm_kernel<<<32, 256, 0, stream>>>(E1p, spos, sii2, acc, done, out);
}